// Round 3
// baseline (665.626 us; speedup 1.0000x reference)
//
#include <hip/hip_runtime.h>
#include <hip/hip_bf16.h>
#include <cstdint>

#define NN 1000000
#define DD 128
#define BB 4096
#define S1C 25
#define S2C 10
#define MM 45056   // BB * (1 + S2C)

using f32x4 = __attribute__((ext_vector_type(4))) float;
using s16x8 = __attribute__((ext_vector_type(8))) short;

__device__ __forceinline__ ushort f2bf(float x) {
    uint32_t u = __float_as_uint(x);
    u += 0x7fff + ((u >> 16) & 1);      // round-to-nearest-even
    return (ushort)(u >> 16);
}
__device__ __forceinline__ float bf2f(ushort h) {
    return __uint_as_float(((uint32_t)h) << 16);
}

// ---------------- Kernel A: layer-1 gather + neighbor mean -> cat1 (bf16 [MM][256])
__global__ __launch_bounds__(256) void k_gather1(
    const float* __restrict__ Z, const int* __restrict__ node_idx,
    const int* __restrict__ nbr1, ushort* __restrict__ cat1)
{
    const int lane = threadIdx.x & 63;
    const int m = blockIdx.x * 4 + (threadIdx.x >> 6);
    const int self = node_idx[m];
    const float2 hs = ((const float2*)(Z + (size_t)self * DD))[lane];
    const int* nb = nbr1 + (size_t)m * S1C;
    float sx = 0.f, sy = 0.f;
    #pragma unroll
    for (int s = 0; s < S1C; ++s) {
        const float2 v = ((const float2*)(Z + (size_t)nb[s] * DD))[lane];
        sx += v.x; sy += v.y;
    }
    const float inv = 1.0f / S1C;
    uint32_t a  = (uint32_t)f2bf(hs.x)     | ((uint32_t)f2bf(hs.y)     << 16);
    uint32_t bm = (uint32_t)f2bf(sx * inv) | ((uint32_t)f2bf(sy * inv) << 16);
    uint32_t* crow = (uint32_t*)(cat1 + (size_t)m * 256);
    crow[lane]      = a;    // h_self -> cols [0,128)
    crow[64 + lane] = bm;   // mean   -> cols [128,256)
}

// ---------------- Kernel C: layer-2 gather over h1 (bf16 [MM][128]) -> cat2 (bf16 [BB][256])
__global__ __launch_bounds__(256) void k_gather2(
    const ushort* __restrict__ h1, const int* __restrict__ nbr2,
    ushort* __restrict__ cat2)
{
    const int lane = threadIdx.x & 63;
    const int b = blockIdx.x * 4 + (threadIdx.x >> 6);
    const uint32_t self = ((const uint32_t*)(h1 + (size_t)b * DD))[lane];
    const int* nb = nbr2 + (size_t)b * S2C;
    float sx = 0.f, sy = 0.f;
    #pragma unroll
    for (int s = 0; s < S2C; ++s) {
        uint32_t v = ((const uint32_t*)(h1 + (size_t)nb[s] * DD))[lane];
        sx += bf2f((ushort)(v & 0xffffu));
        sy += bf2f((ushort)(v >> 16));
    }
    const float inv = 1.0f / S2C;
    uint32_t bm = (uint32_t)f2bf(sx * inv) | ((uint32_t)f2bf(sy * inv) << 16);
    uint32_t* crow = (uint32_t*)(cat2 + (size_t)b * 256);
    crow[lane]      = self;
    crow[64 + lane] = bm;
}

// ---------------- GEMM + sigmoid + L2-normalize.
// rows = gridDim.x*64; C[row][d] = sigmoid( sum_k cat[row][k] * W[d][k] ), then row-normalized.
// W is fp32 [128][256] row-major; staged to LDS as bf16 with XOR swizzle
// (col ^ ((row&7)<<3)) so the B-fragment ds_read_b128 (16 lanes, stride 512B) is conflict-free.
template<int OUT_BF16>
__global__ __launch_bounds__(256) void k_sage(
    const ushort* __restrict__ cat, const float* __restrict__ W,
    void* __restrict__ out)
{
    __shared__ ushort Wl[128][256];   // 64 KB, swizzled
    const int tid = threadIdx.x;
    #pragma unroll
    for (int it = 0; it < 32; ++it) {
        int i = it * 256 + tid;               // float4 index into W
        float4 w = ((const float4*)W)[i];
        int e = i << 2;
        int r = e >> 8, c = e & 255;
        int cs = c ^ ((r & 7) << 3);          // swizzle (moves 8-elem blocks; c%4 preserved)
        ushort4 o;
        o.x = f2bf(w.x); o.y = f2bf(w.y); o.z = f2bf(w.z); o.w = f2bf(w.w);
        *(ushort4*)&Wl[r][cs] = o;
    }
    __syncthreads();

    const int lane = tid & 63;
    const int q = lane >> 4;         // quarter-wave 0..3 -> k-subgroup
    const int p = lane & 15;         // row (A) / col (B) within 16
    const int row0 = blockIdx.x * 64 + (tid >> 6) * 16;

    // A fragment: lane holds row (row0+p), k = ks*32 + q*8 + [0..8)
    const ushort* arow = cat + (size_t)(row0 + p) * 256 + q * 8;
    f32x4 acc[8] = {};
    #pragma unroll
    for (int ks = 0; ks < 8; ++ks) {
        s16x8 a = *(const s16x8*)(arow + ks * 32);
        #pragma unroll
        for (int t = 0; t < 8; ++t) {
            const int d = t * 16 + p;                       // B col = output dim
            const int kcol = (ks * 32 + q * 8) ^ ((d & 7) << 3);
            s16x8 b = *(const s16x8*)&Wl[d][kcol];
            acc[t] = __builtin_amdgcn_mfma_f32_16x16x32_bf16(a, b, acc[t], 0, 0, 0);
        }
    }

    // Epilogue: sigmoid, then L2-normalize each row (row = row0 + q*4 + r, col = t*16 + p).
    float z[8][4];
    float ss[4] = {0.f, 0.f, 0.f, 0.f};
    #pragma unroll
    for (int t = 0; t < 8; ++t)
        #pragma unroll
        for (int r = 0; r < 4; ++r) {
            float v = 1.0f / (1.0f + __expf(-acc[t][r]));
            z[t][r] = v;
            ss[r] += v * v;
        }
    #pragma unroll
    for (int r = 0; r < 4; ++r) {
        float s = ss[r];
        s += __shfl_xor(s, 1);
        s += __shfl_xor(s, 2);
        s += __shfl_xor(s, 4);
        s += __shfl_xor(s, 8);   // reduce across the 16 lanes sharing this output row
        ss[r] = rsqrtf(s);
    }
    #pragma unroll
    for (int t = 0; t < 8; ++t)
        #pragma unroll
        for (int r = 0; r < 4; ++r) {
            int row = row0 + q * 4 + r;
            int col = t * 16 + p;
            float v = z[t][r] * ss[r];
            if (OUT_BF16) ((ushort*)out)[(size_t)row * DD + col] = f2bf(v);
            else          ((float*)out)[(size_t)row * DD + col]  = v;
        }
}

extern "C" void kernel_launch(void* const* d_in, const int* in_sizes, int n_in,
                              void* d_out, int out_size, void* d_ws, size_t ws_size,
                              hipStream_t stream)
{
    const float* Z        = (const float*)d_in[0];
    const float* W1       = (const float*)d_in[1];
    const float* W2       = (const float*)d_in[2];
    const int*   node_idx = (const int*)d_in[3];
    const int*   nbr1     = (const int*)d_in[4];
    const int*   nbr2     = (const int*)d_in[5];

    // ws layout (bf16): cat1 [MM][256] | h1 [MM][128] | cat2 [BB][256]  (~37 MB)
    ushort* cat1 = (ushort*)d_ws;
    ushort* h1   = cat1 + (size_t)MM * 256;
    ushort* cat2 = h1   + (size_t)MM * DD;

    k_gather1<<<MM / 4, 256, 0, stream>>>(Z, node_idx, nbr1, cat1);
    k_sage<1><<<MM / 64, 256, 0, stream>>>(cat1, W1, (void*)h1);
    k_gather2<<<BB / 4, 256, 0, stream>>>(h1, nbr2, cat2);
    k_sage<0><<<BB / 64, 256, 0, stream>>>(cat2, W2, d_out);
}